// Round 1
// baseline (129.295 us; speedup 1.0000x reference)
//
#include <hip/hip_runtime.h>
#include <math.h>

#define TS 4
#define SDIM 128
#define PIX (SDIM * SDIM)
#define TEXW 512
#define TEXH 512
#define EPS 1e-9f
#define NCHUNK 8

// ---------------- Kernel A: bilinear grid sample into ws texture table ------
// tex[s*3+c] = bilinear sample of img (3,512,512) at grid[s] (zero-pad border)
__global__ void tex_sample_kernel(const float* __restrict__ img,
                                  const float* __restrict__ grid,
                                  float* __restrict__ tex, int N) {
#pragma clang fp contract(off)
    int s = blockIdx.x * blockDim.x + threadIdx.x;
    if (s >= N) return;
    float gx = grid[2 * s], gy = grid[2 * s + 1];
    float x = (gx + 1.0f) * (TEXW * 0.5f) - 0.5f;
    float y = (gy + 1.0f) * (TEXH * 0.5f) - 0.5f;
    float x0f = floorf(x), y0f = floorf(y);
    float tx = x - x0f, ty = y - y0f;
    int x0 = (int)x0f, y0 = (int)y0f;
    float w00 = (1.0f - tx) * (1.0f - ty);
    float w10 = tx * (1.0f - ty);
    float w01 = (1.0f - tx) * ty;
    float w11 = tx * ty;
    bool vx0 = (x0 >= 0) && (x0 < TEXW);
    bool vx1 = (x0 + 1 >= 0) && (x0 + 1 < TEXW);
    bool vy0 = (y0 >= 0) && (y0 < TEXH);
    bool vy1 = (y0 + 1 >= 0) && (y0 + 1 < TEXH);
    int xc0 = min(max(x0, 0), TEXW - 1);
    int xc1 = min(max(x0 + 1, 0), TEXW - 1);
    int yc0 = min(max(y0, 0), TEXH - 1);
    int yc1 = min(max(y0 + 1, 0), TEXH - 1);
    float W00 = (vx0 && vy0) ? w00 : 0.0f;
    float W10 = (vx1 && vy0) ? w10 : 0.0f;
    float W01 = (vx0 && vy1) ? w01 : 0.0f;
    float W11 = (vx1 && vy1) ? w11 : 0.0f;
    for (int c = 0; c < 3; ++c) {
        const float* ic = img + c * (TEXH * TEXW);
        float acc = ic[yc0 * TEXW + xc0] * W00;
        acc = acc + ic[yc0 * TEXW + xc1] * W10;
        acc = acc + ic[yc1 * TEXW + xc0] * W01;
        acc = acc + ic[yc1 * TEXW + xc1] * W11;
        tex[s * 3 + c] = acc;
    }
}

// ---------------- Kernel B: camera + per-face 2D setup ----------------------
__device__ inline void cross3(const float a[3], const float b[3], float o[3]) {
    o[0] = a[1] * b[2] - a[2] * b[1];
    o[1] = a[2] * b[0] - a[0] * b[2];
    o[2] = a[0] * b[1] - a[1] * b[0];
}

__global__ void face_setup_kernel(const float* __restrict__ verts,
                                  const int* __restrict__ faces,
                                  const void* __restrict__ azi_p,
                                  const void* __restrict__ ele_p,
                                  float4* __restrict__ fd, int F) {
#pragma clang fp contract(off)
    int f = blockIdx.x * blockDim.x + threadIdx.x;
    if (f >= F) return;
    // azi/ele are 1-element arrays; decode int-vs-float by bit pattern.
    int ai = *(const int*)azi_p;
    float az = (ai > -360000 && ai < 360000) ? (float)ai : *(const float*)azi_p;
    int ei = *(const int*)ele_p;
    float el = (ei > -360000 && ei < 360000) ? (float)ei : *(const float*)ele_p;
    float a = az * (float)(M_PI / 180.0);
    float e = el * (float)(M_PI / 180.0);
    float ca = cosf(a), sa = sinf(a);
    float ce = cosf(e), se = sinf(e);
    float eye[3];
    eye[0] = 2.732f * (ce * sa);
    eye[1] = 2.732f * se;
    eye[2] = 2.732f * ((-ce) * ca);
    float nrm = sqrtf(eye[0] * eye[0] + eye[1] * eye[1] + eye[2] * eye[2]);
    float zv[3] = { (-eye[0]) / nrm, (-eye[1]) / nrm, (-eye[2]) / nrm };
    float up[3] = { 0.0f, 1.0f, 0.0f };
    float xv[3];
    cross3(up, zv, xv);
    float xn = sqrtf(xv[0] * xv[0] + xv[1] * xv[1] + xv[2] * xv[2]);
    xv[0] /= xn; xv[1] /= xn; xv[2] /= xn;
    float yv[3];
    cross3(zv, xv, yv);
    float yn = sqrtf(yv[0] * yv[0] + yv[1] * yv[1] + yv[2] * yv[2]);
    yv[0] /= yn; yv[1] /= yn; yv[2] /= yn;

    float q[3][3];
    for (int k = 0; k < 3; ++k) {
        int vi = faces[f * 3 + k];
        float d0 = verts[vi * 3 + 0] - eye[0];
        float d1 = verts[vi * 3 + 1] - eye[1];
        float d2 = verts[vi * 3 + 2] - eye[2];
        q[k][0] = d0 * xv[0] + d1 * xv[1] + d2 * xv[2];
        q[k][1] = d0 * yv[0] + d1 * yv[1] + d2 * yv[2];
        q[k][2] = d0 * zv[0] + d1 * zv[1] + d2 * zv[2];
    }
    float e1x = q[1][0] - q[0][0], e1y = q[1][1] - q[0][1];
    float e2x = q[2][0] - q[0][0], e2y = q[2][1] - q[0][1];
    float det = e1x * e2y - e1y * e2x;
    float inv = 1.0f / (fabsf(det) > EPS ? det : 1.0f);
    fd[f * 3 + 0] = make_float4(q[0][0], q[0][1], e1x, e1y);
    fd[f * 3 + 1] = make_float4(e2x, e2y, inv, det);
    fd[f * 3 + 2] = make_float4(q[0][2], q[1][2], q[2][2], 0.0f);
}

// ---------------- Kernel C1: rasterize (per face-chunk partial z-min) -------
__global__ void raster_partial_kernel(const float4* __restrict__ fd, int F,
                                      int chunkFaces,
                                      float4* __restrict__ pOut,
                                      int* __restrict__ pFid) {
#pragma clang fp contract(off)
    __shared__ float4 sfd[256 * 3];
    int t = blockIdx.x * blockDim.x + threadIdx.x;  // pixel id
    int chunk = blockIdx.y;
    int f0 = chunk * chunkFaces;
    int f1 = min(f0 + chunkFaces, F);
    int i = t >> 7, j = t & 127;
    float px = ((j + 0.5f) / 128.0f) * 2.0f - 1.0f;
    float py = 1.0f - ((i + 0.5f) / 128.0f) * 2.0f;
    float best = INFINITY;
    int bfid = 0;
    float bw0 = 0.0f, bw1 = 0.0f, bw2 = 0.0f;
    for (int base = f0; base < f1; base += 256) {
        int tn = min(256, f1 - base);
        __syncthreads();
        if ((int)threadIdx.x < tn) {
            sfd[threadIdx.x * 3 + 0] = fd[(base + threadIdx.x) * 3 + 0];
            sfd[threadIdx.x * 3 + 1] = fd[(base + threadIdx.x) * 3 + 1];
            sfd[threadIdx.x * 3 + 2] = fd[(base + threadIdx.x) * 3 + 2];
        }
        __syncthreads();
        for (int k = 0; k < tn; ++k) {
            float4 A = sfd[k * 3 + 0];  // p0x p0y e1x e1y
            float4 B = sfd[k * 3 + 1];  // e2x e2y inv det
            float4 C = sfd[k * 3 + 2];  // z0 z1 z2 -
            float dx = px - A.x, dy = py - A.y;
            float w1 = (dx * B.y - dy * B.x) * B.z;
            float w2 = (A.z * dy - A.w * dx) * B.z;
            float w0 = 1.0f - w1 - w2;
            bool inside = (w0 >= 0.0f) && (w1 >= 0.0f) && (w2 >= 0.0f) &&
                          (fabsf(B.w) > EPS);
            float depth = w0 * C.x + w1 * C.y + w2 * C.z;
            if (inside && depth < best) {
                best = depth;
                bfid = base + k;
                bw0 = w0; bw1 = w1; bw2 = w2;
            }
        }
    }
    pOut[chunk * PIX + t] = make_float4(best, bw0, bw1, bw2);
    pFid[chunk * PIX + t] = bfid;
}

// ---------------- Kernel C2: combine chunks + texture lookup + write --------
__global__ void shade_kernel(const float4* __restrict__ pOut,
                             const int* __restrict__ pFid,
                             const float* __restrict__ tex,
                             float* __restrict__ out, int nChunks) {
#pragma clang fp contract(off)
    int t = blockIdx.x * blockDim.x + threadIdx.x;
    float best = INFINITY;
    int bfid = 0x7fffffff;
    float bw0 = 0.0f, bw1 = 0.0f, bw2 = 0.0f;
    for (int c = 0; c < nChunks; ++c) {
        float4 A = pOut[c * PIX + t];
        int fid = pFid[c * PIX + t];
        // lexicographic (depth, fid) min == first-occurrence argmin
        if (A.x < best || (A.x == best && fid < bfid)) {
            best = A.x; bfid = fid;
            bw0 = A.y; bw1 = A.z; bw2 = A.w;
        }
    }
    bool hit = isfinite(best);
    if (bfid == 0x7fffffff) bfid = 0;
    int i0 = min(max((int)floorf(bw0 * (float)TS), 0), TS - 1);
    int i1 = min(max((int)floorf(bw1 * (float)TS), 0), TS - 1);
    int i2 = min(max((int)floorf(bw2 * (float)TS), 0), TS - 1);
    int sidx = bfid * (TS * TS * TS) + i0 * 16 + i1 * 4 + i2;
    int i = t >> 7, j = t & 127;
    int o = i * SDIM + (SDIM - 1 - j);  // x-flip ([..., ::-1])
    for (int c = 0; c < 3; ++c)
        out[c * PIX + o] = hit ? tex[sidx * 3 + c] : 0.0f;
}

extern "C" void kernel_launch(void* const* d_in, const int* in_sizes, int n_in,
                              void* d_out, int out_size, void* d_ws,
                              size_t ws_size, hipStream_t stream) {
    const float* verts = (const float*)d_in[0];
    const float* img = (const float*)d_in[1];
    const float* grid = (const float*)d_in[2];
    const int* faces = (const int*)d_in[3];
    const void* azi = d_in[4];
    const void* ele = d_in[5];
    float* out = (float*)d_out;

    int N = in_sizes[2] / 2;  // texture grid points (F*64)
    int F = in_sizes[3] / 3;  // faces

    char* ws = (char*)d_ws;
    size_t off = 0;
    float* tex = (float*)(ws + off);
    off += (size_t)N * 3 * sizeof(float);
    off = (off + 15) & ~(size_t)15;
    float4* fd = (float4*)(ws + off);
    off += (size_t)F * 3 * sizeof(float4);
    off = (off + 15) & ~(size_t)15;
    float4* pOut = (float4*)(ws + off);
    off += (size_t)NCHUNK * PIX * sizeof(float4);
    int* pFid = (int*)(ws + off);
    off += (size_t)NCHUNK * PIX * sizeof(int);

    int chunkFaces = (F + NCHUNK - 1) / NCHUNK;

    tex_sample_kernel<<<(N + 255) / 256, 256, 0, stream>>>(img, grid, tex, N);
    face_setup_kernel<<<(F + 255) / 256, 256, 0, stream>>>(verts, faces, azi,
                                                           ele, fd, F);
    raster_partial_kernel<<<dim3(PIX / 256, NCHUNK), 256, 0, stream>>>(
        fd, F, chunkFaces, pOut, pFid);
    shade_kernel<<<PIX / 256, 256, 0, stream>>>(pOut, pFid, tex, out, NCHUNK);
}

// Round 2
// 111.303 us; speedup vs baseline: 1.1616x; 1.1616x over previous
//
#include <hip/hip_runtime.h>
#include <math.h>

#define TS 4
#define SDIM 128
#define PIX (SDIM * SDIM)
#define TEXW 512
#define TEXH 512
#define EPS 1e-9f

// ---------------- Kernel 1: fused prep (texture sample + face setup) --------
// Blocks [0, texBlocks): one thread per (sample, channel); tex planar [c][N].
// Blocks [texBlocks, ...): per-face camera transform + 2D setup, padded to
// Fpad with dummy faces (z=inf, edges=0 -> depth=NaN, never selected).
__device__ inline void cross3(const float a[3], const float b[3], float o[3]) {
    o[0] = a[1] * b[2] - a[2] * b[1];
    o[1] = a[2] * b[0] - a[0] * b[2];
    o[2] = a[0] * b[1] - a[1] * b[0];
}

__global__ void prep_kernel(const float* __restrict__ img,
                            const float* __restrict__ grid,
                            const float* __restrict__ verts,
                            const int* __restrict__ faces,
                            const void* __restrict__ azi_p,
                            const void* __restrict__ ele_p,
                            float* __restrict__ tex, float4* __restrict__ fd,
                            int N, int texBlocks, int F, int Fpad) {
#pragma clang fp contract(off)
    if ((int)blockIdx.x < texBlocks) {
        int t = blockIdx.x * 256 + threadIdx.x;
        if (t >= N * 3) return;
        int c = t / N;
        int s = t - c * N;
        float gx = grid[2 * s], gy = grid[2 * s + 1];
        float x = (gx + 1.0f) * (TEXW * 0.5f) - 0.5f;
        float y = (gy + 1.0f) * (TEXH * 0.5f) - 0.5f;
        float x0f = floorf(x), y0f = floorf(y);
        float tx = x - x0f, ty = y - y0f;
        int x0 = (int)x0f, y0 = (int)y0f;
        float w00 = (1.0f - tx) * (1.0f - ty);
        float w10 = tx * (1.0f - ty);
        float w01 = (1.0f - tx) * ty;
        float w11 = tx * ty;
        bool vx0 = (x0 >= 0) && (x0 < TEXW);
        bool vx1 = (x0 + 1 >= 0) && (x0 + 1 < TEXW);
        bool vy0 = (y0 >= 0) && (y0 < TEXH);
        bool vy1 = (y0 + 1 >= 0) && (y0 + 1 < TEXH);
        int xc0 = min(max(x0, 0), TEXW - 1);
        int xc1 = min(max(x0 + 1, 0), TEXW - 1);
        int yc0 = min(max(y0, 0), TEXH - 1);
        int yc1 = min(max(y0 + 1, 0), TEXH - 1);
        float W00 = (vx0 && vy0) ? w00 : 0.0f;
        float W10 = (vx1 && vy0) ? w10 : 0.0f;
        float W01 = (vx0 && vy1) ? w01 : 0.0f;
        float W11 = (vx1 && vy1) ? w11 : 0.0f;
        const float* ic = img + c * (TEXH * TEXW);
        float acc = ic[yc0 * TEXW + xc0] * W00;
        acc = acc + ic[yc0 * TEXW + xc1] * W10;
        acc = acc + ic[yc1 * TEXW + xc0] * W01;
        acc = acc + ic[yc1 * TEXW + xc1] * W11;
        tex[c * N + s] = acc;
    } else {
        int f = (blockIdx.x - texBlocks) * 256 + threadIdx.x;
        if (f >= Fpad) return;
        if (f >= F) {
            // dummy face: w1=w2=0, w0=1, depth = 1*inf + 0*inf = NaN
            fd[f * 3 + 0] = make_float4(0.0f, 0.0f, 0.0f, 0.0f);
            fd[f * 3 + 1] = make_float4(0.0f, 0.0f, 1.0f, 0.0f);
            fd[f * 3 + 2] = make_float4(INFINITY, INFINITY, INFINITY, 0.0f);
            return;
        }
        int ai = *(const int*)azi_p;
        float az = (ai > -360000 && ai < 360000) ? (float)ai
                                                 : *(const float*)azi_p;
        int ei = *(const int*)ele_p;
        float el = (ei > -360000 && ei < 360000) ? (float)ei
                                                 : *(const float*)ele_p;
        float a = az * (float)(M_PI / 180.0);
        float e = el * (float)(M_PI / 180.0);
        float ca = cosf(a), sa = sinf(a);
        float ce = cosf(e), se = sinf(e);
        float eye[3];
        eye[0] = 2.732f * (ce * sa);
        eye[1] = 2.732f * se;
        eye[2] = 2.732f * ((-ce) * ca);
        float nrm = sqrtf(eye[0] * eye[0] + eye[1] * eye[1] + eye[2] * eye[2]);
        float zv[3] = { (-eye[0]) / nrm, (-eye[1]) / nrm, (-eye[2]) / nrm };
        float up[3] = { 0.0f, 1.0f, 0.0f };
        float xv[3];
        cross3(up, zv, xv);
        float xn = sqrtf(xv[0] * xv[0] + xv[1] * xv[1] + xv[2] * xv[2]);
        xv[0] /= xn; xv[1] /= xn; xv[2] /= xn;
        float yv[3];
        cross3(zv, xv, yv);
        float yn = sqrtf(yv[0] * yv[0] + yv[1] * yv[1] + yv[2] * yv[2]);
        yv[0] /= yn; yv[1] /= yn; yv[2] /= yn;

        float q[3][3];
        for (int k = 0; k < 3; ++k) {
            int vi = faces[f * 3 + k];
            float d0 = verts[vi * 3 + 0] - eye[0];
            float d1 = verts[vi * 3 + 1] - eye[1];
            float d2 = verts[vi * 3 + 2] - eye[2];
            q[k][0] = d0 * xv[0] + d1 * xv[1] + d2 * xv[2];
            q[k][1] = d0 * yv[0] + d1 * yv[1] + d2 * yv[2];
            q[k][2] = d0 * zv[0] + d1 * zv[1] + d2 * zv[2];
        }
        float e1x = q[1][0] - q[0][0], e1y = q[1][1] - q[0][1];
        float e2x = q[2][0] - q[0][0], e2y = q[2][1] - q[0][1];
        float det = e1x * e2y - e1y * e2x;
        bool valid = fabsf(det) > EPS;
        float inv = 1.0f / (valid ? det : 1.0f);
        // invalid det -> z=inf so depth is inf/NaN -> never selected
        float z0 = valid ? q[0][2] : INFINITY;
        float z1 = valid ? q[1][2] : INFINITY;
        float z2 = valid ? q[2][2] : INFINITY;
        fd[f * 3 + 0] = make_float4(q[0][0], q[0][1], e1x, e1y);
        fd[f * 3 + 1] = make_float4(e2x, e2y, inv, 0.0f);
        fd[f * 3 + 2] = make_float4(z0, z1, z2, 0.0f);
    }
}

// ---------------- Kernel 2: rasterize (per face-chunk partial z-min) --------
// grid = (PIX/256, nchunk); chunkFaces <= 256 (fd padded to nchunk*chunkFaces)
__global__ void raster_kernel(const float4* __restrict__ fd, int chunkFaces,
                              uint2* __restrict__ partial) {
#pragma clang fp contract(off)
    __shared__ float4 sfd[256 * 3];
    int t = blockIdx.x * 256 + threadIdx.x;  // pixel id
    int chunk = blockIdx.y;
    int f0 = chunk * chunkFaces;
    if ((int)threadIdx.x < chunkFaces) {
        sfd[threadIdx.x * 3 + 0] = fd[(f0 + threadIdx.x) * 3 + 0];
        sfd[threadIdx.x * 3 + 1] = fd[(f0 + threadIdx.x) * 3 + 1];
        sfd[threadIdx.x * 3 + 2] = fd[(f0 + threadIdx.x) * 3 + 2];
    }
    __syncthreads();
    int i = t >> 7, j = t & 127;
    float px = ((j + 0.5f) / 128.0f) * 2.0f - 1.0f;
    float py = 1.0f - ((i + 0.5f) / 128.0f) * 2.0f;
    float best = INFINITY;
    int bfid = 0;
    for (int k = 0; k < chunkFaces; ++k) {
        float4 A = sfd[k * 3 + 0];  // p0x p0y e1x e1y
        float4 B = sfd[k * 3 + 1];  // e2x e2y inv -
        float4 C = sfd[k * 3 + 2];  // z0 z1 z2 -
        float dx = px - A.x, dy = py - A.y;
        float w1 = (dx * B.y - dy * B.x) * B.z;
        float w2 = (A.z * dy - A.w * dx) * B.z;
        float w0 = 1.0f - w1 - w2;
        bool inside = (w0 >= 0.0f) && (w1 >= 0.0f) && (w2 >= 0.0f);
        float depth = w0 * C.x + w1 * C.y + w2 * C.z;
        if (inside && depth < best) {  // strict < keeps first (lowest fid)
            best = depth;
            bfid = f0 + k;
        }
    }
    partial[chunk * PIX + t] = make_uint2(__float_as_uint(best), (uint)bfid);
}

// ---------------- Kernel 3: combine chunks + texture lookup + write --------
__global__ void shade_kernel(const uint2* __restrict__ partial,
                             const float4* __restrict__ fd,
                             const float* __restrict__ tex,
                             float* __restrict__ out, int nChunks, int N) {
#pragma clang fp contract(off)
    int t = blockIdx.x * 256 + threadIdx.x;
    float best = INFINITY;
    int bfid = 0;
    for (int c = 0; c < nChunks; ++c) {
        uint2 P = partial[c * PIX + t];
        float d = __uint_as_float(P.x);
        if (d < best) {  // ascending chunk scan: strict < keeps first min
            best = d;
            bfid = (int)P.y;
        }
    }
    bool hit = isfinite(best);
    // recompute barycentrics for the winning face (bit-identical exprs)
    float4 A = fd[bfid * 3 + 0];
    float4 B = fd[bfid * 3 + 1];
    int i = t >> 7, j = t & 127;
    float px = ((j + 0.5f) / 128.0f) * 2.0f - 1.0f;
    float py = 1.0f - ((i + 0.5f) / 128.0f) * 2.0f;
    float dx = px - A.x, dy = py - A.y;
    float w1 = (dx * B.y - dy * B.x) * B.z;
    float w2 = (A.z * dy - A.w * dx) * B.z;
    float w0 = 1.0f - w1 - w2;
    int i0 = min(max((int)floorf(w0 * (float)TS), 0), TS - 1);
    int i1 = min(max((int)floorf(w1 * (float)TS), 0), TS - 1);
    int i2 = min(max((int)floorf(w2 * (float)TS), 0), TS - 1);
    int sidx = bfid * (TS * TS * TS) + i0 * 16 + i1 * 4 + i2;
    int o = i * SDIM + (SDIM - 1 - j);  // x-flip ([..., ::-1])
    for (int c = 0; c < 3; ++c)
        out[c * PIX + o] = hit ? tex[c * N + sidx] : 0.0f;
}

extern "C" void kernel_launch(void* const* d_in, const int* in_sizes, int n_in,
                              void* d_out, int out_size, void* d_ws,
                              size_t ws_size, hipStream_t stream) {
    const float* verts = (const float*)d_in[0];
    const float* img = (const float*)d_in[1];
    const float* grid = (const float*)d_in[2];
    const int* faces = (const int*)d_in[3];
    const void* azi = d_in[4];
    const void* ele = d_in[5];
    float* out = (float*)d_out;

    int N = in_sizes[2] / 2;  // texture grid points (F*64)
    int F = in_sizes[3] / 3;  // faces

    // choose nchunk to fit ws; chunkFaces must stay <= 256 (nchunk >= 8)
    int nchunk = 32, chunkFaces, Fpad;
    for (;;) {
        chunkFaces = (F + nchunk - 1) / nchunk;
        Fpad = nchunk * chunkFaces;
        size_t need = (((size_t)N * 3 * 4 + 15) & ~(size_t)15) +
                      (((size_t)Fpad * 3 * 16 + 15) & ~(size_t)15) +
                      (size_t)nchunk * PIX * 8;
        if (need <= ws_size || nchunk <= 8) break;
        nchunk >>= 1;
    }

    char* ws = (char*)d_ws;
    size_t off = 0;
    float* tex = (float*)(ws + off);
    off += ((size_t)N * 3 * 4 + 15) & ~(size_t)15;
    float4* fd = (float4*)(ws + off);
    off += ((size_t)Fpad * 3 * 16 + 15) & ~(size_t)15;
    uint2* partial = (uint2*)(ws + off);

    int texBlocks = (N * 3 + 255) / 256;
    int faceBlocks = (Fpad + 255) / 256;

    prep_kernel<<<texBlocks + faceBlocks, 256, 0, stream>>>(
        img, grid, verts, faces, azi, ele, tex, fd, N, texBlocks, F, Fpad);
    raster_kernel<<<dim3(PIX / 256, nchunk), 256, 0, stream>>>(fd, chunkFaces,
                                                               partial);
    shade_kernel<<<PIX / 256, 256, 0, stream>>>(partial, fd, tex, out, nchunk,
                                                N);
}

// Round 3
// 91.828 us; speedup vs baseline: 1.4080x; 1.2121x over previous
//
#include <hip/hip_runtime.h>
#include <math.h>

#define TS 4
#define SDIM 128
#define PIX (SDIM * SDIM)
#define TEXW 512
#define TEXH 512
#define EPS 1e-9f
#define NCHUNK 32
#define NTILE 64  // 8x8 tiles of 16x16 pixels
#define BBOX_MARGIN 1e-3f

// ---------------- Kernel 1: face setup + zbuf init --------------------------
__device__ inline void cross3(const float a[3], const float b[3], float o[3]) {
    o[0] = a[1] * b[2] - a[2] * b[1];
    o[1] = a[2] * b[0] - a[0] * b[2];
    o[2] = a[0] * b[1] - a[1] * b[0];
}

__global__ void setup_kernel(const float* __restrict__ verts,
                             const int* __restrict__ faces,
                             const void* __restrict__ azi_p,
                             const void* __restrict__ ele_p,
                             float4* __restrict__ fd,
                             unsigned long long* __restrict__ zbuf,
                             int F, int faceBlocks) {
#pragma clang fp contract(off)
    if ((int)blockIdx.x >= faceBlocks) {
        int t = (blockIdx.x - faceBlocks) * 256 + threadIdx.x;
        if (t < PIX) zbuf[t] = ~0ull;
        return;
    }
    int f = blockIdx.x * 256 + threadIdx.x;
    if (f >= F) return;
    // azi/ele are 1-element arrays; decode int-vs-float by bit pattern.
    int ai = *(const int*)azi_p;
    float az = (ai > -360000 && ai < 360000) ? (float)ai : *(const float*)azi_p;
    int ei = *(const int*)ele_p;
    float el = (ei > -360000 && ei < 360000) ? (float)ei : *(const float*)ele_p;
    float a = az * (float)(M_PI / 180.0);
    float e = el * (float)(M_PI / 180.0);
    float ca = cosf(a), sa = sinf(a);
    float ce = cosf(e), se = sinf(e);
    float eye[3];
    eye[0] = 2.732f * (ce * sa);
    eye[1] = 2.732f * se;
    eye[2] = 2.732f * ((-ce) * ca);
    float nrm = sqrtf(eye[0] * eye[0] + eye[1] * eye[1] + eye[2] * eye[2]);
    float zv[3] = { (-eye[0]) / nrm, (-eye[1]) / nrm, (-eye[2]) / nrm };
    float up[3] = { 0.0f, 1.0f, 0.0f };
    float xv[3];
    cross3(up, zv, xv);
    float xn = sqrtf(xv[0] * xv[0] + xv[1] * xv[1] + xv[2] * xv[2]);
    xv[0] /= xn; xv[1] /= xn; xv[2] /= xn;
    float yv[3];
    cross3(zv, xv, yv);
    float yn = sqrtf(yv[0] * yv[0] + yv[1] * yv[1] + yv[2] * yv[2]);
    yv[0] /= yn; yv[1] /= yn; yv[2] /= yn;

    float q[3][3];
    for (int k = 0; k < 3; ++k) {
        int vi = faces[f * 3 + k];
        float d0 = verts[vi * 3 + 0] - eye[0];
        float d1 = verts[vi * 3 + 1] - eye[1];
        float d2 = verts[vi * 3 + 2] - eye[2];
        q[k][0] = d0 * xv[0] + d1 * xv[1] + d2 * xv[2];
        q[k][1] = d0 * yv[0] + d1 * yv[1] + d2 * yv[2];
        q[k][2] = d0 * zv[0] + d1 * zv[1] + d2 * zv[2];
    }
    float e1x = q[1][0] - q[0][0], e1y = q[1][1] - q[0][1];
    float e2x = q[2][0] - q[0][0], e2y = q[2][1] - q[0][1];
    float det = e1x * e2y - e1y * e2x;
    bool valid = fabsf(det) > EPS;
    float inv = 1.0f / (valid ? det : 1.0f);
    // invalid det -> z=inf so depth is inf/NaN -> never selected
    float z0 = valid ? q[0][2] : INFINITY;
    float z1 = valid ? q[1][2] : INFINITY;
    float z2 = valid ? q[2][2] : INFINITY;
    fd[f * 3 + 0] = make_float4(q[0][0], q[0][1], e1x, e1y);
    fd[f * 3 + 1] = make_float4(e2x, e2y, inv, 0.0f);
    fd[f * 3 + 2] = make_float4(z0, z1, z2, 0.0f);
}

// monotone float->uint encoding (works for any sign; NaN excluded by caller)
__device__ inline unsigned int enc_depth(float d) {
    unsigned int u = __float_as_uint(d);
    return (u & 0x80000000u) ? ~u : (u | 0x80000000u);
}

// ---------------- Kernel 2: tiled raster w/ bbox cull + atomicMin zbuf ------
// grid = (NTILE, nchunk); block = 256 = one 16x16-pixel tile
__global__ void raster_kernel(const float4* __restrict__ fd, int F,
                              int chunkFaces,
                              unsigned long long* __restrict__ zbuf) {
#pragma clang fp contract(off)
    __shared__ float4 sfd[256 * 3];
    int tileX = blockIdx.x & 7, tileY = blockIdx.x >> 3;
    int f0 = blockIdx.y * chunkFaces;
    // tile NDC bounds (pixel centers)
    float xlo = (tileX * 16 + 0.5f) / 64.0f - 1.0f - BBOX_MARGIN;
    float xhi = (tileX * 16 + 15.5f) / 64.0f - 1.0f + BBOX_MARGIN;
    float yhi = 1.0f - (tileY * 16 + 0.5f) / 64.0f + BBOX_MARGIN;
    float ylo = 1.0f - (tileY * 16 + 15.5f) / 64.0f - BBOX_MARGIN;
    for (int k = threadIdx.x; k < chunkFaces; k += 256) {
        int f = f0 + k;
        float flag = 0.0f;
        float4 A, B, C;
        if (f < F) {
            A = fd[f * 3 + 0];  // p0x p0y e1x e1y
            B = fd[f * 3 + 1];  // e2x e2y inv -
            C = fd[f * 3 + 2];  // z0 z1 z2 -
            float p1x = A.x + A.z, p1y = A.y + A.w;
            float p2x = A.x + B.x, p2y = A.y + B.y;
            float bxmin = fminf(A.x, fminf(p1x, p2x));
            float bxmax = fmaxf(A.x, fmaxf(p1x, p2x));
            float bymin = fminf(A.y, fminf(p1y, p2y));
            float bymax = fmaxf(A.y, fmaxf(p1y, p2y));
            if (bxmin <= xhi && bxmax >= xlo && bymin <= yhi && bymax >= ylo)
                flag = 1.0f;
        } else {
            A = make_float4(0.f, 0.f, 0.f, 0.f);
            B = make_float4(0.f, 0.f, 1.f, 0.f);
            C = make_float4(0.f, 0.f, 0.f, 0.f);
        }
        B.w = flag;
        sfd[k * 3 + 0] = A;
        sfd[k * 3 + 1] = B;
        sfd[k * 3 + 2] = C;
    }
    __syncthreads();
    int j = tileX * 16 + (threadIdx.x & 15);
    int i = tileY * 16 + (threadIdx.x >> 4);
    float px = ((j + 0.5f) / 128.0f) * 2.0f - 1.0f;
    float py = 1.0f - ((i + 0.5f) / 128.0f) * 2.0f;
    float best = INFINITY;
    int bfid = 0x7fffffff;
    bool have = false;
    for (int k = 0; k < chunkFaces; ++k) {
        float4 B = sfd[k * 3 + 1];
        if (B.w == 0.0f) continue;  // wave-uniform skip (culled face)
        float4 A = sfd[k * 3 + 0];
        float4 C = sfd[k * 3 + 2];
        float dx = px - A.x, dy = py - A.y;
        float w1 = (dx * B.y - dy * B.x) * B.z;
        float w2 = (A.z * dy - A.w * dx) * B.z;
        float w0 = 1.0f - w1 - w2;
        bool inside = (w0 >= 0.0f) && (w1 >= 0.0f) && (w2 >= 0.0f);
        float depth = w0 * C.x + w1 * C.y + w2 * C.z;
        int f = f0 + k;
        // lexicographic (depth, fid): order-independent == first-min argmin
        if (inside && depth < INFINITY &&
            (depth < best || (depth == best && f < bfid))) {
            best = depth;
            bfid = f;
            have = true;
        }
    }
    if (have) {
        unsigned long long pack =
            ((unsigned long long)enc_depth(best) << 32) | (unsigned int)bfid;
        atomicMin(&zbuf[i * SDIM + j], pack);
    }
}

// ---------------- Kernel 3: shade (decode zbuf + on-demand bilinear) --------
__global__ void shade_kernel(const unsigned long long* __restrict__ zbuf,
                             const float4* __restrict__ fd,
                             const float* __restrict__ img,
                             const float* __restrict__ grid,
                             float* __restrict__ out) {
#pragma clang fp contract(off)
    int t = blockIdx.x * 256 + threadIdx.x;
    int i = t >> 7, j = t & 127;
    int o = i * SDIM + (SDIM - 1 - j);  // x-flip ([..., ::-1])
    unsigned long long pack = zbuf[t];
    if (pack == ~0ull) {  // no finite hit
        out[0 * PIX + o] = 0.0f;
        out[1 * PIX + o] = 0.0f;
        out[2 * PIX + o] = 0.0f;
        return;
    }
    int bfid = (int)(unsigned int)(pack & 0xffffffffu);
    // recompute barycentrics for winning face (bit-identical exprs)
    float4 A = fd[bfid * 3 + 0];
    float4 B = fd[bfid * 3 + 1];
    float px = ((j + 0.5f) / 128.0f) * 2.0f - 1.0f;
    float py = 1.0f - ((i + 0.5f) / 128.0f) * 2.0f;
    float dx = px - A.x, dy = py - A.y;
    float w1 = (dx * B.y - dy * B.x) * B.z;
    float w2 = (A.z * dy - A.w * dx) * B.z;
    float w0 = 1.0f - w1 - w2;
    int i0 = min(max((int)floorf(w0 * (float)TS), 0), TS - 1);
    int i1 = min(max((int)floorf(w1 * (float)TS), 0), TS - 1);
    int i2 = min(max((int)floorf(w2 * (float)TS), 0), TS - 1);
    int sidx = bfid * (TS * TS * TS) + i0 * 16 + i1 * 4 + i2;
    // on-demand bilinear sample (bit-identical to reference grid_sample)
    float gx = grid[2 * sidx], gy = grid[2 * sidx + 1];
    float x = (gx + 1.0f) * (TEXW * 0.5f) - 0.5f;
    float y = (gy + 1.0f) * (TEXH * 0.5f) - 0.5f;
    float x0f = floorf(x), y0f = floorf(y);
    float tx = x - x0f, ty = y - y0f;
    int x0 = (int)x0f, y0 = (int)y0f;
    float w00 = (1.0f - tx) * (1.0f - ty);
    float w10 = tx * (1.0f - ty);
    float w01 = (1.0f - tx) * ty;
    float w11 = tx * ty;
    bool vx0 = (x0 >= 0) && (x0 < TEXW);
    bool vx1 = (x0 + 1 >= 0) && (x0 + 1 < TEXW);
    bool vy0 = (y0 >= 0) && (y0 < TEXH);
    bool vy1 = (y0 + 1 >= 0) && (y0 + 1 < TEXH);
    int xc0 = min(max(x0, 0), TEXW - 1);
    int xc1 = min(max(x0 + 1, 0), TEXW - 1);
    int yc0 = min(max(y0, 0), TEXH - 1);
    int yc1 = min(max(y0 + 1, 0), TEXH - 1);
    float W00 = (vx0 && vy0) ? w00 : 0.0f;
    float W10 = (vx1 && vy0) ? w10 : 0.0f;
    float W01 = (vx0 && vy1) ? w01 : 0.0f;
    float W11 = (vx1 && vy1) ? w11 : 0.0f;
    for (int c = 0; c < 3; ++c) {
        const float* ic = img + c * (TEXH * TEXW);
        float acc = ic[yc0 * TEXW + xc0] * W00;
        acc = acc + ic[yc0 * TEXW + xc1] * W10;
        acc = acc + ic[yc1 * TEXW + xc0] * W01;
        acc = acc + ic[yc1 * TEXW + xc1] * W11;
        out[c * PIX + o] = acc;
    }
}

extern "C" void kernel_launch(void* const* d_in, const int* in_sizes, int n_in,
                              void* d_out, int out_size, void* d_ws,
                              size_t ws_size, hipStream_t stream) {
    const float* verts = (const float*)d_in[0];
    const float* img = (const float*)d_in[1];
    const float* grid = (const float*)d_in[2];
    const int* faces = (const int*)d_in[3];
    const void* azi = d_in[4];
    const void* ele = d_in[5];
    float* out = (float*)d_out;

    int F = in_sizes[3] / 3;  // faces

    char* ws = (char*)d_ws;
    size_t off = 0;
    float4* fd = (float4*)(ws + off);
    off += ((size_t)F * 3 * 16 + 255) & ~(size_t)255;
    unsigned long long* zbuf = (unsigned long long*)(ws + off);

    int faceBlocks = (F + 255) / 256;
    int zBlocks = (PIX + 255) / 256;
    int chunkFaces = (F + NCHUNK - 1) / NCHUNK;

    setup_kernel<<<faceBlocks + zBlocks, 256, 0, stream>>>(
        verts, faces, azi, ele, fd, zbuf, F, faceBlocks);
    raster_kernel<<<dim3(NTILE, NCHUNK), 256, 0, stream>>>(fd, F, chunkFaces,
                                                           zbuf);
    shade_kernel<<<PIX / 256, 256, 0, stream>>>(zbuf, fd, img, grid, out);
}